// Round 1
// 1635.337 us; speedup vs baseline: 1.1868x; 1.1868x over previous
//
#include <hip/hip_runtime.h>
#include <stdint.h>
#include <math.h>

// Problem constants (fixed by setup_inputs)
#define H_IMG 256
#define W_IMG 128
#define LTOK  32768
#define BATCH 4
#define CDIM  256
#define HIDDIM 1024
#define NHEAD 8
#define HD    32
#define MROWS 131072   // B * L

typedef __attribute__((ext_vector_type(8))) short short8;
typedef __attribute__((ext_vector_type(4))) float f32x4;

// ---------- helpers ----------
__device__ __forceinline__ float bf2f(unsigned u) {
  union { unsigned u; float f; } c; c.u = u << 16; return c.f;
}
__device__ __forceinline__ unsigned short f2bf(float f) {
  union { float f; unsigned u; } c; c.f = f;
  unsigned r = c.u + 0x7fffu + ((c.u >> 16) & 1u);  // RNE
  return (unsigned short)(r >> 16);
}
__device__ __forceinline__ float gelu_f(float x) {
  return 0.5f * x * (1.0f + erff(x * 0.70710678118654752f));
}
__device__ __forceinline__ void gload_lds16(const void* g, void* l) {
  __builtin_amdgcn_global_load_lds(
      (const __attribute__((address_space(1))) unsigned int*)g,
      (__attribute__((address_space(3))) unsigned int*)l, 16, 0, 0);
}

// ---------- weight convert: f32 [K,N] -> bf16 [N,K] (transpose) ----------
__global__ __launch_bounds__(256) void wconv_kernel(
    const float* __restrict__ w, unsigned short* __restrict__ wt, int K, int N) {
  __shared__ float t[32][33];
  const int k0 = blockIdx.x * 32, n0 = blockIdx.y * 32;
  const int tx = threadIdx.x & 31, ty = threadIdx.x >> 5;
#pragma unroll
  for (int i = 0; i < 4; ++i)
    t[ty + 8 * i][tx] = w[(size_t)(k0 + ty + 8 * i) * N + n0 + tx];
  __syncthreads();
#pragma unroll
  for (int i = 0; i < 4; ++i)
    wt[(size_t)(n0 + ty + 8 * i) * K + k0 + tx] = f2bf(t[tx][ty + 8 * i]);
}

// ---------- LayerNorm (fp32 in -> bf16 out), one wave per row of C=256 ----------
__global__ __launch_bounds__(256) void ln_kernel(
    const float* __restrict__ x, const float* __restrict__ g,
    const float* __restrict__ b, unsigned short* __restrict__ out) {
  const int wave = threadIdx.x >> 6;
  const int lane = threadIdx.x & 63;
  const size_t row = (size_t)blockIdx.x * 4 + wave;
  float4 f = ((const float4*)(x + row * CDIM))[lane];
  float s  = f.x + f.y + f.z + f.w;
  float sq = f.x*f.x + f.y*f.y + f.z*f.z + f.w*f.w;
#pragma unroll
  for (int o = 32; o > 0; o >>= 1) { s += __shfl_down(s, o); sq += __shfl_down(sq, o); }
  s = __shfl(s, 0); sq = __shfl(sq, 0);
  const float mu = s * (1.0f / CDIM);
  const float var = sq * (1.0f / CDIM) - mu * mu;
  const float rstd = rsqrtf(var + 1e-5f);
  float4 gg = ((const float4*)g)[lane];
  float4 bb = ((const float4*)b)[lane];
  unsigned short o4[4];
  o4[0] = f2bf((f.x - mu) * rstd * gg.x + bb.x);
  o4[1] = f2bf((f.y - mu) * rstd * gg.y + bb.y);
  o4[2] = f2bf((f.z - mu) * rstd * gg.z + bb.z);
  o4[3] = f2bf((f.w - mu) * rstd * gg.w + bb.w);
  *(uint2*)(out + row * CDIM + lane * 4) = *(uint2*)o4;
}

// ---------- MFMA GEMM: out[M,:] = A[M,K](bf16) @ Bt[N,K](bf16)^T + bias ----------
template<int EPI>
__global__ __launch_bounds__(256) void mgemm(
    const unsigned short* __restrict__ A, const unsigned short* __restrict__ Bt,
    const float* __restrict__ bias, float bscale, const float* __restrict__ res,
    void* __restrict__ outp, int K, int ldc) {
  __shared__ unsigned short As[128][32];
  __shared__ unsigned short Bs[128][32];
  const int tid = threadIdx.x;
  const int w = tid >> 6, lane = tid & 63;
  const int m0 = blockIdx.x * 128, n0 = blockIdx.y * 128;
  const int wm = (w & 1) * 64, wn = (w >> 1) * 64;
  const int srow = lane >> 2;                 // 0..15 within a 16-row chunk
  const int csrc = (lane & 3) ^ (srow & 3);   // swizzled source 16B-chunk
  f32x4 acc[4][4];
#pragma unroll
  for (int mi = 0; mi < 4; ++mi)
#pragma unroll
    for (int ni = 0; ni < 4; ++ni)
#pragma unroll
      for (int r = 0; r < 4; ++r) acc[mi][ni][r] = 0.0f;

  const int kg = lane >> 4, ml = lane & 15;
  for (int kk = 0; kk < K; kk += 32) {
#pragma unroll
    for (int i = 0; i < 2; ++i) {
      const int rl = w * 32 + i * 16 + srow;       // local row 0..127
      gload_lds16(A + (size_t)(m0 + rl) * K + kk + csrc * 8, &As[w * 32 + i * 16][0]);
      gload_lds16(Bt + (size_t)(n0 + rl) * K + kk + csrc * 8, &Bs[w * 32 + i * 16][0]);
    }
    __syncthreads();
    short8 af[4], bg[4];
#pragma unroll
    for (int mi = 0; mi < 4; ++mi) {
      const int r = wm + mi * 16 + ml;
      af[mi] = *(const short8*)&As[r][(kg ^ (r & 3)) * 8];
    }
#pragma unroll
    for (int ni = 0; ni < 4; ++ni) {
      const int r = wn + ni * 16 + ml;
      bg[ni] = *(const short8*)&Bs[r][(kg ^ (r & 3)) * 8];
    }
#pragma unroll
    for (int mi = 0; mi < 4; ++mi)
#pragma unroll
      for (int ni = 0; ni < 4; ++ni)
        acc[mi][ni] = __builtin_amdgcn_mfma_f32_16x16x32_bf16(af[mi], bg[ni], acc[mi][ni], 0, 0, 0);
    __syncthreads();
  }
  // epilogue: C/D layout col=lane&15, row=(lane>>4)*4+r
#pragma unroll
  for (int ni = 0; ni < 4; ++ni) {
    const int n = n0 + wn + ni * 16 + ml;
    const float bn = bias[n] * bscale;
#pragma unroll
    for (int mi = 0; mi < 4; ++mi) {
#pragma unroll
      for (int r = 0; r < 4; ++r) {
        const int m = m0 + wm + mi * 16 + kg * 4 + r;
        const size_t idx = (size_t)m * ldc + n;
        float val = acc[mi][ni][r] + bn;
        if (EPI == 1) {
          ((float*)outp)[idx] = val + res[idx];
        } else if (EPI == 2) {
          ((unsigned short*)outp)[idx] = f2bf(gelu_f(val));
        } else {
          ((unsigned short*)outp)[idx] = f2bf(val);
        }
      }
    }
  }
}

// ---------- Window attention via MFMA (k = q shared) ----------
// One block = one window (256 thr = 4 waves); wave w does heads {w, w+4}.
// Per wave: Q head-slice [64][32] staged via global_load_lds; V staged
// TRANSPOSED [32][72] via reg round-trip (B-fragment reads bank-even);
// QK^T = 16 mfma_16x16x32 (same fragments serve A and B since k=q);
// softmax on C-layout rows (3 fmax + shfl_xor 1/2/4/8); P->bf16 into LDS
// with 16B-chunk XOR swizzle (chunk ^= row&7) overlaying dead Q/V staging;
// PV = 16 mfma; O restaged through LDS for coalesced 64B/lane global write.
// All LDS traffic is wave-private -> no __syncthreads in the hot loop.
__global__ __launch_bounds__(256, 3) void attn_kernel(
    const unsigned short* __restrict__ q, const unsigned short* __restrict__ v,
    const float* __restrict__ rpb, const int* __restrict__ pHo,
    const int* __restrict__ pWo, unsigned short* __restrict__ yout) {
  __shared__ char wbuf[4][8704];     // per-wave: qh[64][32] | vt[32][72]; P/Ost overlay
  __shared__ float bias_w[4][228];   // per-wave rpb slice (225 used)
  __shared__ int reg_s[64];
  const int tid = threadIdx.x;
  const int w = tid >> 6, lane = tid & 63;
  const int g = lane >> 4, c = lane & 15;
  const int wb = blockIdx.x;         // b*512 + wh*16 + ww
  const int b = wb >> 9, wloc = wb & 511;
  const int wh = wloc >> 4, ww = wloc & 15;
  const int Ho = pHo[0], Wo = pWo[0];
  const int dy = lane >> 3, dx = lane & 7;
  const int hr = wh * 8 + dy, wr = ww * 8 + dx;   // rolled coords (lane = token)
  int ho = hr + Ho; if (ho >= H_IMG) ho -= H_IMG;
  int wo = wr + Wo; if (wo >= W_IMG) wo -= W_IMG;
  const size_t tok = (size_t)b * LTOK + (size_t)ho * W_IMG + wo;
  const bool edge = (wh == (H_IMG / 8 - 1)) || (ww == (W_IMG / 8 - 1));
  if (w == 0) {
    const int rh = (hr < H_IMG - 8) ? 0 : ((hr < H_IMG - Ho) ? 1 : 2);
    const int rw = (wr < W_IMG - 8) ? 0 : ((wr < W_IMG - Wo) ? 1 : 2);
    reg_s[lane] = rh * 3 + rw;
  }
  __syncthreads();

  unsigned short* qh = (unsigned short*)&wbuf[w][0];      // [64][32]
  unsigned short* vt = (unsigned short*)&wbuf[w][4096];   // [32][72] (V^T, padded)
  unsigned short* Pp = (unsigned short*)&wbuf[w][0];      // [64][64] swizzled overlay

  const float scale = 0.17677669529663687f;  // 32^-0.5
  const int dxk = c & 7, dyk0 = c >> 3;
  const int base_l = 112 - dyk0 * 15 - dxk;  // rel = Aq + base_l - 30*nj

  for (int p2 = 0; p2 < 2; ++p2) {
    const int hh = w + 4 * p2;
    // ---- V global loads first (oldest in vmcnt FIFO -> drained for vt writes) ----
    const uint4* vp = (const uint4*)(v + tok * CDIM + hh * HD);
    uint4 a0 = vp[0], a1 = vp[1], a2 = vp[2], a3 = vp[3];
    // ---- bias slice (wave-private) ----
#pragma unroll
    for (int i = 0; i < 4; ++i) {
      const int idx = lane + 64 * i;
      if (idx < 225) bias_w[w][idx] = rpb[idx * 8 + hh];
    }
    // ---- stage Q head-slice via global_load_lds (lane -> token 16u+(l>>2), chunk l&3) ----
#pragma unroll
    for (int u = 0; u < 4; ++u) {
      const int t2 = u * 16 + (lane >> 2);
      int ho2 = wh * 8 + (t2 >> 3) + Ho; if (ho2 >= H_IMG) ho2 -= H_IMG;
      int wo2 = ww * 8 + (t2 & 7) + Wo;  if (wo2 >= W_IMG) wo2 -= W_IMG;
      const size_t tk = (size_t)b * LTOK + (size_t)ho2 * W_IMG + wo2;
      gload_lds16(q + tk * CDIM + hh * HD + (lane & 3) * 8, &qh[u * 512]);
    }
    // ---- write V transposed: vt[d][token], row-uniform b16 stores (no conflicts) ----
    {
      unsigned tmp[16] = {a0.x,a0.y,a0.z,a0.w,a1.x,a1.y,a1.z,a1.w,
                          a2.x,a2.y,a2.z,a2.w,a3.x,a3.y,a3.z,a3.w};
#pragma unroll
      for (int d2 = 0; d2 < 16; ++d2) {
        vt[(2 * d2) * 72 + lane]     = (unsigned short)(tmp[d2] & 0xffffu);
        vt[(2 * d2 + 1) * 72 + lane] = (unsigned short)(tmp[d2] >> 16);
      }
    }
    asm volatile("s_waitcnt vmcnt(0)" ::: "memory");  // Q DMA landed
    // ---- fragments (A/B layouts identical; k=q -> one set both sides) ----
    short8 q4[4];
#pragma unroll
    for (int mi = 0; mi < 4; ++mi)
      q4[mi] = *(const short8*)&qh[(16 * mi + c) * 32 + g * 8];
    short8 vf[2][2];
#pragma unroll
    for (int s2 = 0; s2 < 2; ++s2)
#pragma unroll
      for (int n2 = 0; n2 < 2; ++n2)
        vf[s2][n2] = *(const short8*)&vt[(16 * n2 + c) * 72 + 32 * s2 + 8 * g];
    // ---- QK^T: S[q-tile mi][k-tile nj] ----
    f32x4 acc[4][4];
#pragma unroll
    for (int mi = 0; mi < 4; ++mi)
#pragma unroll
      for (int nj = 0; nj < 4; ++nj)
#pragma unroll
        for (int r = 0; r < 4; ++r) acc[mi][nj][r] = 0.0f;
#pragma unroll
    for (int mi = 0; mi < 4; ++mi)
#pragma unroll
      for (int nj = 0; nj < 4; ++nj)
        acc[mi][nj] = __builtin_amdgcn_mfma_f32_16x16x32_bf16(q4[mi], q4[nj], acc[mi][nj], 0, 0, 0);
    int regk[4];
    if (edge) {
#pragma unroll
      for (int nj = 0; nj < 4; ++nj) regk[nj] = reg_s[16 * nj + c];
    }
    // ---- softmax per row (C-layout: row q=16mi+4g+r, col kt=16nj+c) + P write ----
#pragma unroll
    for (int mi = 0; mi < 4; ++mi) {
#pragma unroll
      for (int r = 0; r < 4; ++r) {
        const int qq = 16 * mi + 4 * g + r;
        const int rb = (qq >> 3) * 15 + (qq & 7) + base_l;
        float sv[4];
#pragma unroll
        for (int nj = 0; nj < 4; ++nj)
          sv[nj] = acc[mi][nj][r] * scale + bias_w[w][rb - 30 * nj];
        if (edge) {
          const int regq = reg_s[qq];
#pragma unroll
          for (int nj = 0; nj < 4; ++nj)
            if (regq != regk[nj]) sv[nj] -= 100.0f;
        }
        float mx2 = fmaxf(fmaxf(sv[0], sv[1]), fmaxf(sv[2], sv[3]));
        mx2 = fmaxf(mx2, __shfl_xor(mx2, 1));
        mx2 = fmaxf(mx2, __shfl_xor(mx2, 2));
        mx2 = fmaxf(mx2, __shfl_xor(mx2, 4));
        mx2 = fmaxf(mx2, __shfl_xor(mx2, 8));
        float e0 = __expf(sv[0] - mx2), e1 = __expf(sv[1] - mx2);
        float e2 = __expf(sv[2] - mx2), e3 = __expf(sv[3] - mx2);
        float sm = e0 + e1 + e2 + e3;
        sm += __shfl_xor(sm, 1);
        sm += __shfl_xor(sm, 2);
        sm += __shfl_xor(sm, 4);
        sm += __shfl_xor(sm, 8);
        const float iv = __builtin_amdgcn_rcpf(sm);
        const int rowoff = qq * 64, sw = qq & 7;
        Pp[rowoff + ((dyk0 ^ sw) * 8)       + dxk] = f2bf(e0 * iv);
        Pp[rowoff + (((2 + dyk0) ^ sw) * 8) + dxk] = f2bf(e1 * iv);
        Pp[rowoff + (((4 + dyk0) ^ sw) * 8) + dxk] = f2bf(e2 * iv);
        Pp[rowoff + (((6 + dyk0) ^ sw) * 8) + dxk] = f2bf(e3 * iv);
      }
    }
    // ---- PV: O[q-tile mi][d-tile n2] over 2 K-steps ----
    f32x4 oacc[4][2];
#pragma unroll
    for (int mi = 0; mi < 4; ++mi)
#pragma unroll
      for (int n2 = 0; n2 < 2; ++n2)
#pragma unroll
        for (int r = 0; r < 4; ++r) oacc[mi][n2][r] = 0.0f;
#pragma unroll
    for (int s2 = 0; s2 < 2; ++s2) {
      short8 pa[4];
#pragma unroll
      for (int mi = 0; mi < 4; ++mi) {
        const int qq2 = 16 * mi + c;
        pa[mi] = *(const short8*)&Pp[qq2 * 64 + (((4 * s2 + g) ^ (qq2 & 7)) * 8)];
      }
#pragma unroll
      for (int mi = 0; mi < 4; ++mi)
#pragma unroll
        for (int n2 = 0; n2 < 2; ++n2)
          oacc[mi][n2] = __builtin_amdgcn_mfma_f32_16x16x32_bf16(pa[mi], vf[s2][n2], oacc[mi][n2], 0, 0, 0);
    }
    // ---- epilogue: restage O [64][40] in LDS, then 4x16B coalesced global ----
    unsigned short* Ost = Pp;
#pragma unroll
    for (int mi = 0; mi < 4; ++mi)
#pragma unroll
      for (int n2 = 0; n2 < 2; ++n2)
#pragma unroll
        for (int r = 0; r < 4; ++r)
          Ost[(16 * mi + 4 * g + r) * 40 + 16 * n2 + c] = f2bf(oacc[mi][n2][r]);
    uint4* op = (uint4*)(yout + tok * CDIM + hh * HD);
#pragma unroll
    for (int u = 0; u < 4; ++u)
      op[u] = *(const uint4*)&Ost[lane * 40 + u * 8];
  }
}

// ---------- Depthwise 3x3 conv on a row band (full 1024 ch) + GELU ----------
__global__ __launch_bounds__(256) void dwconv_kernel(
    const unsigned short* __restrict__ t1b, const float* __restrict__ k9,
    const float* __restrict__ bias, unsigned short* __restrict__ t2b,
    int hr0, int band_rows) {
  const int c = blockIdx.y * 128 + (threadIdx.x & 31) * 4;
  const int tok = blockIdx.x * 8 + (threadIdx.x >> 5);   // 0..band_rows*128-1
  const int h = hr0 + (tok >> 7), wcol = tok & 127;
  float wreg[4][9];
#pragma unroll
  for (int j = 0; j < 4; ++j)
#pragma unroll
    for (int tp = 0; tp < 9; ++tp) wreg[j][tp] = k9[(c + j) * 9 + tp];
  const float4 bv = *(const float4*)(bias + c);
  float a0 = 0, a1 = 0, a2 = 0, a3 = 0;
#pragma unroll
  for (int ky = 0; ky < 3; ++ky) {
    const int hy = h + ky - 1;
    if ((unsigned)hy >= (unsigned)H_IMG) continue;
    const int brow = (tok >> 7) + ky;   // buffer row
#pragma unroll
    for (int kx = 0; kx < 3; ++kx) {
      const int wx = wcol + kx - 1;
      if ((unsigned)wx >= (unsigned)W_IMG) continue;
      const ushort4 tv = *(const ushort4*)(
          t1b + ((size_t)(brow * 128 + wx)) * HIDDIM + c);
      const int tp = ky * 3 + kx;
      a0 += bf2f(tv.x) * wreg[0][tp];
      a1 += bf2f(tv.y) * wreg[1][tp];
      a2 += bf2f(tv.z) * wreg[2][tp];
      a3 += bf2f(tv.w) * wreg[3][tp];
    }
  }
  a0 = gelu_f(a0 + bv.x); a1 = gelu_f(a1 + bv.y);
  a2 = gelu_f(a2 + bv.z); a3 = gelu_f(a3 + bv.w);
  unsigned short o[4] = { f2bf(a0), f2bf(a1), f2bf(a2), f2bf(a3) };
  *(uint2*)(t2b + (size_t)tok * HIDDIM + c) = *(uint2*)o;
}

// ---------- launch ----------
extern "C" void kernel_launch(void* const* d_in, const int* in_sizes, int n_in,
                              void* d_out, int out_size, void* d_ws, size_t ws_size,
                              hipStream_t stream) {
  (void)in_sizes; (void)n_in; (void)out_size; (void)ws_size;
  const float* x     = (const float*)d_in[0];
  const float* n1g   = (const float*)d_in[1];
  const float* n1b   = (const float*)d_in[2];
  const float* wq    = (const float*)d_in[3];
  const float* bq    = (const float*)d_in[4];
  const float* wv    = (const float*)d_in[5];
  const float* bv    = (const float*)d_in[6];
  const float* rpb   = (const float*)d_in[7];
  const float* wproj = (const float*)d_in[8];
  const float* bproj = (const float*)d_in[9];
  const float* n2g   = (const float*)d_in[10];
  const float* n2b   = (const float*)d_in[11];
  const float* w1    = (const float*)d_in[12];
  const float* b1    = (const float*)d_in[13];
  const float* dwk   = (const float*)d_in[14];
  const float* dwb   = (const float*)d_in[15];
  const float* w2    = (const float*)d_in[16];
  const float* b2    = (const float*)d_in[17];
  const int*   pHo   = (const int*)d_in[18];
  const int*   pWo   = (const int*)d_in[19];
  float* out = (float*)d_out;

  char* wsb = (char*)d_ws;
  unsigned short* r0     = (unsigned short*)wsb;
  unsigned short* wqt    = (unsigned short*)(wsb + 67108864ull);
  unsigned short* wvt    = (unsigned short*)(wsb + 67108864ull + 131072ull);
  unsigned short* wprojt = (unsigned short*)(wsb + 67108864ull + 262144ull);
  unsigned short* w1t    = (unsigned short*)(wsb + 67108864ull + 393216ull);
  unsigned short* w2t    = (unsigned short*)(wsb + 67108864ull + 917504ull);
  unsigned short* t1b    = (unsigned short*)(wsb + 68550656ull);
  unsigned short* t2b    = (unsigned short*)(wsb + 68550656ull + 25690112ull);
  unsigned short* vb     = (unsigned short*)d_out;
  unsigned short* qb     = (unsigned short*)((char*)d_out + 67108864ull);

  // 0. weight convert + transpose (f32 [K,N] -> bf16 [N,K])
  wconv_kernel<<<dim3(8, 8),  256, 0, stream>>>(wq,    wqt,    CDIM, CDIM);
  wconv_kernel<<<dim3(8, 8),  256, 0, stream>>>(wv,    wvt,    CDIM, CDIM);
  wconv_kernel<<<dim3(8, 8),  256, 0, stream>>>(wproj, wprojt, CDIM, CDIM);
  wconv_kernel<<<dim3(8, 32), 256, 0, stream>>>(w1,    w1t,    CDIM, HIDDIM);
  wconv_kernel<<<dim3(32, 8), 256, 0, stream>>>(w2,    w2t,    HIDDIM, CDIM);

  // 1. LN1: x -> xn (r0)
  ln_kernel<<<32768, 256, 0, stream>>>(x, n1g, n1b, r0);
  // 2-3. q,v projections (bf16 out into d_out halves)
  mgemm<0><<<dim3(1024, 2), 256, 0, stream>>>(r0, wqt, bq, 1.0f, nullptr, qb, CDIM, CDIM);
  mgemm<0><<<dim3(1024, 2), 256, 0, stream>>>(r0, wvt, bv, 1.0f, nullptr, vb, CDIM, CDIM);
  // 4. window attention (k = q) -> yattn (r0; xn dead)
  attn_kernel<<<dim3(2048), 256, 0, stream>>>(qb, vb, rpb, pHo, pWo, r0);
  // 5. xattn = x + yattn@wproj + bproj -> d_out f32 (q/v dead)
  mgemm<1><<<dim3(1024, 2), 256, 0, stream>>>(r0, wprojt, bproj, 1.0f, x, out, CDIM, CDIM);
  // 6. LN2: d_out -> xn2 (r0)
  ln_kernel<<<32768, 256, 0, stream>>>(out, n2g, n2b, r0);
  // 7-9. LeFF over row bands
  for (int bi = 0; bi < BATCH; ++bi) {
    for (int hr0 = 0; hr0 < H_IMG; ) {
      const int br = (H_IMG - hr0 >= 96) ? 96 : (H_IMG - hr0);
      const int r_start = (hr0 > 0) ? hr0 - 1 : 0;
      const int r_end = (hr0 + br <= H_IMG - 1) ? hr0 + br : H_IMG - 1;
      const int nrows = r_end - r_start + 1;
      const unsigned short* Aff1 = r0 + ((size_t)bi * LTOK + (size_t)r_start * W_IMG) * CDIM;
      unsigned short* t1dst = t1b + (size_t)(r_start - hr0 + 1) * W_IMG * HIDDIM;
      mgemm<2><<<dim3(nrows, 8), 256, 0, stream>>>(
          Aff1, w1t, b1, 1.0f, nullptr, t1dst, CDIM, HIDDIM);
      dwconv_kernel<<<dim3(br * 16, 8), 256, 0, stream>>>(t1b, dwk, dwb, t2b, hr0, br);
      const size_t btok = (size_t)bi * LTOK + (size_t)hr0 * W_IMG;
      mgemm<1><<<dim3(br, 2), 256, 0, stream>>>(
          t2b, w2t, b2, 1.0f, out + btok * CDIM, out + btok * CDIM, HIDDIM, CDIM);
      hr0 += br;
    }
  }
}